// Round 1
// baseline (1176.544 us; speedup 1.0000x reference)
//
#include <hip/hip_runtime.h>

#define B_DIM 8
#define L_DIM 4096
#define D_DIM 1024
#define S_DIM 256
#define N_DIM 3

#define ROWS 64   // rows of X per workgroup
#define KB   32   // K-block staged in LDS
#define NT   256  // threads per workgroup

__device__ __forceinline__ float4 ld4(const float* p) {
    return *reinterpret_cast<const float4*>(p);
}

// Kernel 1: fused GEMM + argmax.
// best[t*3 + i] = argmax_s ( dot(x[t,:], mem[s,i,:]) + pb[s,i] )  for t in [0, B*L)
__global__ __launch_bounds__(NT, 2)
void score_argmax_kernel(const float* __restrict__ x,
                         const float* __restrict__ mem,
                         const float* __restrict__ pb,
                         int* __restrict__ best)
{
    // k-major tiles: conflict-free float4 reads in the inner loop
    __shared__ float aL[KB][ROWS];    // 8 KB
    __shared__ float bL[KB][S_DIM];   // 32 KB
    __shared__ float redv[ROWS][16];  // 4 KB
    __shared__ int   redi[ROWS][16];  // 4 KB

    const int tid = threadIdx.x;
    const int tx = tid & 15;    // column group: s = 16*tx + c
    const int ty = tid >> 4;    // row group:    row = 4*ty + r
    const int t0 = blockIdx.x * ROWS;

    for (int i = 0; i < N_DIM; ++i) {
        float accm[4][16];
        #pragma unroll
        for (int r = 0; r < 4; ++r)
            #pragma unroll
            for (int c = 0; c < 16; ++c) accm[r][c] = 0.0f;

        for (int k0 = 0; k0 < D_DIM; k0 += KB) {
            __syncthreads();  // protect LDS tiles from previous iteration's readers

            // stage A tile (ROWS x KB), transposed to k-major: 2 float4 per thread
            #pragma unroll
            for (int p = 0; p < (ROWS * KB / 4) / NT; ++p) {
                const int f4  = tid + p * NT;
                const int row = f4 >> 3;
                const int kq  = (f4 & 7) << 2;
                const float4 v = ld4(x + (t0 + row) * D_DIM + k0 + kq);
                aL[kq + 0][row] = v.x;
                aL[kq + 1][row] = v.y;
                aL[kq + 2][row] = v.z;
                aL[kq + 3][row] = v.w;
            }
            // stage B tile (S_DIM x KB) for this i, k-major: 8 float4 per thread
            #pragma unroll
            for (int p = 0; p < (S_DIM * KB / 4) / NT; ++p) {
                const int f4 = tid + p * NT;
                const int s  = f4 >> 3;
                const int kq = (f4 & 7) << 2;
                const float4 v = ld4(mem + (s * N_DIM + i) * D_DIM + k0 + kq);
                bL[kq + 0][s] = v.x;
                bL[kq + 1][s] = v.y;
                bL[kq + 2][s] = v.z;
                bL[kq + 3][s] = v.w;
            }
            __syncthreads();

            // fresh accumulator bank per K-block (blocked summation: keeps
            // rounding error ~1e-5 so the argmax matches the numpy fp32 ref)
            float accb[4][16];
            #pragma unroll
            for (int r = 0; r < 4; ++r)
                #pragma unroll
                for (int c = 0; c < 16; ++c) accb[r][c] = 0.0f;

            #pragma unroll 8
            for (int k = 0; k < KB; ++k) {
                const float4 a4 = *reinterpret_cast<const float4*>(&aL[k][ty * 4]);
                const float ar[4] = {a4.x, a4.y, a4.z, a4.w};
                #pragma unroll
                for (int q = 0; q < 4; ++q) {
                    const float4 b4 = *reinterpret_cast<const float4*>(&bL[k][tx * 16 + q * 4]);
                    #pragma unroll
                    for (int r = 0; r < 4; ++r) {
                        accb[r][q * 4 + 0] += ar[r] * b4.x;
                        accb[r][q * 4 + 1] += ar[r] * b4.y;
                        accb[r][q * 4 + 2] += ar[r] * b4.z;
                        accb[r][q * 4 + 3] += ar[r] * b4.w;
                    }
                }
            }
            #pragma unroll
            for (int r = 0; r < 4; ++r)
                #pragma unroll
                for (int c = 0; c < 16; ++c) accm[r][c] += accb[r][c];
        }

        // epilogue: add pos_bias, per-thread argmax over this thread's 16 s values
        #pragma unroll
        for (int r = 0; r < 4; ++r) {
            float bv = -INFINITY;
            int bs = 0;
            #pragma unroll
            for (int c = 0; c < 16; ++c) {
                const int s = tx * 16 + c;
                const float v = accm[r][c] + pb[s * N_DIM + i];
                if (v > bv) { bv = v; bs = s; }  // ascending s + strict > => first max
            }
            redv[ty * 4 + r][tx] = bv;
            redi[ty * 4 + r][tx] = bs;
        }
        __syncthreads();
        if (tid < ROWS) {
            float bv = redv[tid][0];
            int bs = redi[tid][0];
            #pragma unroll
            for (int j = 1; j < 16; ++j) {
                const float v = redv[tid][j];
                const int s = redi[tid][j];
                if (v > bv || (v == bv && s < bs)) { bv = v; bs = s; }
            }
            best[(t0 + tid) * N_DIM + i] = bs;
        }
        __syncthreads();
    }
}

// Kernel 2: out[b,l,:] = sum_i mem[best_i, i, :]
__global__ __launch_bounds__(NT)
void gather_sum_kernel(const float* __restrict__ mem,
                       const float* __restrict__ pb,
                       const int* __restrict__ best,
                       float* __restrict__ out)
{
    const int bl = blockIdx.x;        // b*L + l
    const int l = bl & (L_DIM - 1);
    __shared__ int sbi[N_DIM];
    if (threadIdx.x < N_DIM) {
        const int i = threadIdx.x;
        const int t = l + i - (N_DIM - 1);
        int bi;
        if (t >= 0) {
            bi = best[(bl + i - (N_DIM - 1)) * N_DIM + i];
        } else {
            // zero ngram row: argmax over pos_bias only (rare: l < 2)
            float bv = pb[i];
            bi = 0;
            for (int s = 1; s < S_DIM; ++s) {
                const float v = pb[s * N_DIM + i];
                if (v > bv) { bv = v; bi = s; }
            }
        }
        sbi[i] = bi;
    }
    __syncthreads();
    const int d = threadIdx.x;  // 256 threads x float4 = 1024 floats
    const float4 v0 = ld4(mem + (sbi[0] * N_DIM + 0) * D_DIM + d * 4);
    const float4 v1 = ld4(mem + (sbi[1] * N_DIM + 1) * D_DIM + d * 4);
    const float4 v2 = ld4(mem + (sbi[2] * N_DIM + 2) * D_DIM + d * 4);
    float4 r;
    r.x = (v0.x + v1.x) + v2.x;
    r.y = (v0.y + v1.y) + v2.y;
    r.z = (v0.z + v1.z) + v2.z;
    r.w = (v0.w + v1.w) + v2.w;
    *reinterpret_cast<float4*>(out + bl * D_DIM + d * 4) = r;
}

extern "C" void kernel_launch(void* const* d_in, const int* in_sizes, int n_in,
                              void* d_out, int out_size, void* d_ws, size_t ws_size,
                              hipStream_t stream)
{
    const float* x   = (const float*)d_in[0];   // (B, L, D) fp32
    const float* mem = (const float*)d_in[1];   // (S, N, D) fp32
    const float* pb  = (const float*)d_in[2];   // (S, N) fp32
    float* out = (float*)d_out;                 // (B, L, D) fp32
    int* best = (int*)d_ws;                     // B*L*3 ints = 384 KB scratch

    const int n_rows = B_DIM * L_DIM;           // 32768
    score_argmax_kernel<<<dim3(n_rows / ROWS), dim3(NT), 0, stream>>>(x, mem, pb, best);
    gather_sum_kernel<<<dim3(n_rows), dim3(NT), 0, stream>>>(mem, pb, best, out);
}

// Round 2
// 893.300 us; speedup vs baseline: 1.3171x; 1.3171x over previous
//
#include <hip/hip_runtime.h>

#define B_DIM 8
#define L_DIM 4096
#define D_DIM 1024
#define S_DIM 256
#define N_DIM 3

#define ROWS 64   // rows of X per workgroup
#define KB   32   // K-block staged in LDS
#define NT   256  // threads per workgroup

__device__ __forceinline__ float4 ld4(const float* p) {
    return *reinterpret_cast<const float4*>(p);
}

// Kernel 1: fused GEMM + argmax, one i (ngram offset) per blockIdx.y.
// best[t*3 + i] = argmax_s ( dot(x[t,:], mem[s,i,:]) + pb[s,i] )
//
// LDS layout: k-major tiles, XOR-swizzled by sw(k) = k & ~3 so that both
// the transpose-staging scalar writes AND the inner-loop b128 reads are
// bank-conflict-free (<=2-way, which is free on gfx950 per m136).
// Thread (tx,ty) computes rows {4ty+r} x cols {q*64 + tx*4 + j}  (4x16).
__global__ __launch_bounds__(NT, 2)
void score_argmax_kernel(const float* __restrict__ x,
                         const float* __restrict__ mem,
                         const float* __restrict__ pb,
                         int* __restrict__ best)
{
    __shared__ float aL[KB][ROWS];    // 8 KB  (swizzled)
    __shared__ float bL[KB][S_DIM];   // 32 KB (swizzled)

    const int tid = threadIdx.x;
    const int tx = tid & 15;    // column group: s = q*64 + tx*4 + j
    const int ty = tid >> 4;    // row group:    row = 4*ty + r
    const int t0 = blockIdx.x * ROWS;
    const int i  = blockIdx.y;  // ngram offset 0..2

    // pos_bias for this thread's 16 columns (tiny, L2-cached, once per block)
    float pbv[16];
    #pragma unroll
    for (int q = 0; q < 4; ++q)
        #pragma unroll
        for (int j = 0; j < 4; ++j)
            pbv[q * 4 + j] = pb[(q * 64 + tx * 4 + j) * N_DIM + i];

    float accm[4][16];
    #pragma unroll
    for (int r = 0; r < 4; ++r)
        #pragma unroll
        for (int c = 0; c < 16; ++c) accm[r][c] = 0.0f;

    for (int k0 = 0; k0 < D_DIM; k0 += KB) {
        __syncthreads();  // protect LDS tiles from previous iteration's readers

        // stage A tile (ROWS x KB) transposed to k-major, swizzled: 2 float4/thread
        #pragma unroll
        for (int p = 0; p < (ROWS * KB / 4) / NT; ++p) {
            const int f4  = tid + p * NT;
            const int row = f4 >> 3;           // 8 rows per wave -> coalesced global
            const int kq  = (f4 & 7) << 2;     // kq = sw(k) for all 4 lanes' k
            const float4 v = ld4(x + (t0 + row) * D_DIM + k0 + kq);
            aL[kq + 0][row ^ kq] = v.x;
            aL[kq + 1][row ^ kq] = v.y;
            aL[kq + 2][row ^ kq] = v.z;
            aL[kq + 3][row ^ kq] = v.w;
        }
        // stage B tile (S_DIM x KB), k-major, swizzled: 8 float4/thread
        #pragma unroll
        for (int p = 0; p < (S_DIM * KB / 4) / NT; ++p) {
            const int f4 = tid + p * NT;
            const int s  = f4 >> 3;
            const int kq = (f4 & 7) << 2;
            const float4 v = ld4(mem + (s * N_DIM + i) * D_DIM + k0 + kq);
            bL[kq + 0][s ^ kq] = v.x;
            bL[kq + 1][s ^ kq] = v.y;
            bL[kq + 2][s ^ kq] = v.z;
            bL[kq + 3][s ^ kq] = v.w;
        }
        __syncthreads();

        // fresh accumulator bank per K-block (blocked summation keeps rounding
        // error ~1e-5 so the argmax matches the numpy fp32 ref exactly)
        float accb[4][16];
        #pragma unroll
        for (int r = 0; r < 4; ++r)
            #pragma unroll
            for (int c = 0; c < 16; ++c) accb[r][c] = 0.0f;

        #pragma unroll 8
        for (int k = 0; k < KB; ++k) {
            const int sw = k & ~3;  // compile-time per unroll instance
            const float4 a4 = *reinterpret_cast<const float4*>(&aL[k][(ty * 4) ^ sw]);
            const float ar[4] = {a4.x, a4.y, a4.z, a4.w};
            #pragma unroll
            for (int q = 0; q < 4; ++q) {
                const float4 b4 = *reinterpret_cast<const float4*>(&bL[k][(q * 64 + tx * 4) ^ sw]);
                #pragma unroll
                for (int r = 0; r < 4; ++r) {
                    accb[r][q * 4 + 0] += ar[r] * b4.x;
                    accb[r][q * 4 + 1] += ar[r] * b4.y;
                    accb[r][q * 4 + 2] += ar[r] * b4.z;
                    accb[r][q * 4 + 3] += ar[r] * b4.w;
                }
            }
        }
        #pragma unroll
        for (int r = 0; r < 4; ++r)
            #pragma unroll
            for (int c = 0; c < 16; ++c) accm[r][c] += accb[r][c];
    }

    // epilogue: add pos_bias, per-thread argmax over 16 columns (s ascending
    // in (q,j) order + strict '>' == numpy first-max), then 16-lane shuffle
    // reduce (the 16 column-threads of a row are consecutive lanes).
    #pragma unroll
    for (int r = 0; r < 4; ++r) {
        float bv = -INFINITY;
        int bs = 0;
        #pragma unroll
        for (int q = 0; q < 4; ++q)
            #pragma unroll
            for (int j = 0; j < 4; ++j) {
                const int s = q * 64 + tx * 4 + j;
                const float v = accm[r][q * 4 + j] + pbv[q * 4 + j];
                if (v > bv) { bv = v; bs = s; }
            }
        #pragma unroll
        for (int off = 8; off >= 1; off >>= 1) {
            const float ov = __shfl_xor(bv, off);
            const int   os = __shfl_xor(bs, off);
            if (ov > bv || (ov == bv && os < bs)) { bv = ov; bs = os; }
        }
        if (tx == 0) best[(t0 + ty * 4 + r) * N_DIM + i] = bs;
    }
}

// Kernel 2: out[b,l,:] = sum_i mem[best_i, i, :]
__global__ __launch_bounds__(NT)
void gather_sum_kernel(const float* __restrict__ mem,
                       const float* __restrict__ pb,
                       const int* __restrict__ best,
                       float* __restrict__ out)
{
    const int bl = blockIdx.x;        // b*L + l
    const int l = bl & (L_DIM - 1);
    __shared__ int sbi[N_DIM];
    if (threadIdx.x < N_DIM) {
        const int i = threadIdx.x;
        const int t = l + i - (N_DIM - 1);
        int bi;
        if (t >= 0) {
            bi = best[(bl + i - (N_DIM - 1)) * N_DIM + i];
        } else {
            // zero ngram row: argmax over pos_bias only (rare: l < 2)
            float bv = pb[i];
            bi = 0;
            for (int s = 1; s < S_DIM; ++s) {
                const float v = pb[s * N_DIM + i];
                if (v > bv) { bv = v; bi = s; }
            }
        }
        sbi[i] = bi;
    }
    __syncthreads();
    const int d = threadIdx.x;  // 256 threads x float4 = 1024 floats
    const float4 v0 = ld4(mem + (sbi[0] * N_DIM + 0) * D_DIM + d * 4);
    const float4 v1 = ld4(mem + (sbi[1] * N_DIM + 1) * D_DIM + d * 4);
    const float4 v2 = ld4(mem + (sbi[2] * N_DIM + 2) * D_DIM + d * 4);
    float4 r;
    r.x = (v0.x + v1.x) + v2.x;
    r.y = (v0.y + v1.y) + v2.y;
    r.z = (v0.z + v1.z) + v2.z;
    r.w = (v0.w + v1.w) + v2.w;
    *reinterpret_cast<float4*>(out + bl * D_DIM + d * 4) = r;
}

extern "C" void kernel_launch(void* const* d_in, const int* in_sizes, int n_in,
                              void* d_out, int out_size, void* d_ws, size_t ws_size,
                              hipStream_t stream)
{
    const float* x   = (const float*)d_in[0];   // (B, L, D) fp32
    const float* mem = (const float*)d_in[1];   // (S, N, D) fp32
    const float* pb  = (const float*)d_in[2];   // (S, N) fp32
    float* out = (float*)d_out;                 // (B, L, D) fp32
    int* best = (int*)d_ws;                     // B*L*3 ints = 384 KB scratch

    const int n_rows = B_DIM * L_DIM;           // 32768
    score_argmax_kernel<<<dim3(n_rows / ROWS, N_DIM), dim3(NT), 0, stream>>>(x, mem, pb, best);
    gather_sum_kernel<<<dim3(n_rows), dim3(NT), 0, stream>>>(mem, pb, best, out);
}